// Round 1
// baseline (663.057 us; speedup 1.0000x reference)
//
#include <hip/hip_runtime.h>

#define DIMSZ 2048
#define NH 32
#define NKV 8
#define HD 64
#define SEQLEN 2048
#define BATCH 2
#define NROWS (BATCH*SEQLEN)   // 4096
#define NQKVC 3072             // 2048 q + 512 k + 512 v

typedef __bf16 bf16x8 __attribute__((ext_vector_type(8)));
typedef float f32x4v __attribute__((ext_vector_type(4)));

__device__ __forceinline__ unsigned short f2bf(float f) {
  union { float f; unsigned int u; } v; v.f = f;
  return (unsigned short)((v.u + 0x7FFFu + ((v.u >> 16) & 1u)) >> 16);
}
__device__ __forceinline__ float bf2f(unsigned int bits16) {
  union { unsigned int u; float f; } v; v.u = bits16 << 16; return v.f;
}
// XOR swizzle for LDS tiles with 128-byte rows: spreads 16 same-column rows
// across 8 distinct 16B slots (2-way residual conflict is free per m136).
__device__ __forceinline__ int swz128(int row, int colBytes) {
  return row * 128 + (colBytes ^ ((row & 7) << 4));
}

// ---------------- fp32 -> bf16 convert (vectorized x4) ----------------
__global__ void k_cvt(const float* __restrict__ s, unsigned short* __restrict__ d, int n4) {
  int i = blockIdx.x * 256 + threadIdx.x;
  if (i >= n4) return;
  float4 v = reinterpret_cast<const float4*>(s)[i];
  unsigned long long pk =
      (unsigned long long)f2bf(v.x) |
      ((unsigned long long)f2bf(v.y) << 16) |
      ((unsigned long long)f2bf(v.z) << 32) |
      ((unsigned long long)f2bf(v.w) << 48);
  reinterpret_cast<unsigned long long*>(d)[i] = pk;
}

// ---------------- GEMM: C[M][N] = A[M][K] * B[N][K]^T (bf16 in, fp32 acc) ----------------
// 128x128 tile, BK=64, 4 waves each computing a 64x64 quadrant via 4x4 16x16x32 MFMA frags.
template<int OUT_BF16>
__global__ __launch_bounds__(256, 2) void k_gemm_bt(
    const unsigned short* __restrict__ A,
    const unsigned short* __restrict__ B,
    void* __restrict__ Cv, int M, int N, int K)
{
  constexpr int BK = 64;
  __shared__ __attribute__((aligned(16))) unsigned short smA[128 * BK];
  __shared__ __attribute__((aligned(16))) unsigned short smB[128 * BK];
  const int tid = threadIdx.x;
  const int lane = tid & 63;
  const int wid = tid >> 6;
  const int lr = lane & 15, lg = lane >> 4;
  const int m0 = blockIdx.y * 128, n0 = blockIdx.x * 128;
  const int wr = (wid >> 1) * 64, wc = (wid & 1) * 64;

  f32x4v acc[4][4];
  #pragma unroll
  for (int i = 0; i < 4; i++)
    #pragma unroll
    for (int j = 0; j < 4; j++)
      acc[i][j] = f32x4v{0.f, 0.f, 0.f, 0.f};

  for (int k0 = 0; k0 < K; k0 += BK) {
    uint4 ra[4], rb[4];
    #pragma unroll
    for (int i = 0; i < 4; i++) {
      const int c = i * 256 + tid;
      const int row = c >> 3, kc = c & 7;
      ra[i] = *reinterpret_cast<const uint4*>(A + (size_t)(m0 + row) * K + k0 + kc * 8);
      rb[i] = *reinterpret_cast<const uint4*>(B + (size_t)(n0 + row) * K + k0 + kc * 8);
    }
    __syncthreads();   // previous iteration's LDS reads done
    #pragma unroll
    for (int i = 0; i < 4; i++) {
      const int c = i * 256 + tid;
      const int row = c >> 3, kc = c & 7;
      *reinterpret_cast<uint4*>((char*)smA + swz128(row, kc * 16)) = ra[i];
      *reinterpret_cast<uint4*>((char*)smB + swz128(row, kc * 16)) = rb[i];
    }
    __syncthreads();   // tile staged
    #pragma unroll
    for (int ks = 0; ks < 2; ks++) {
      bf16x8 af[4], bfv[4];
      #pragma unroll
      for (int m = 0; m < 4; m++)
        af[m] = *reinterpret_cast<const bf16x8*>((char*)smA + swz128(wr + m * 16 + lr, ks * 64 + lg * 16));
      #pragma unroll
      for (int n = 0; n < 4; n++)
        bfv[n] = *reinterpret_cast<const bf16x8*>((char*)smB + swz128(wc + n * 16 + lr, ks * 64 + lg * 16));
      #pragma unroll
      for (int m = 0; m < 4; m++)
        #pragma unroll
        for (int n = 0; n < 4; n++)
          acc[m][n] = __builtin_amdgcn_mfma_f32_16x16x32_bf16(af[m], bfv[n], acc[m][n], 0, 0, 0);
    }
  }
  #pragma unroll
  for (int m = 0; m < 4; m++)
    #pragma unroll
    for (int n = 0; n < 4; n++)
      #pragma unroll
      for (int r = 0; r < 4; r++) {
        const size_t row = m0 + wr + m * 16 + lg * 4 + r;  // C/D: row=(l>>4)*4+r (m89/m91)
        const size_t col = n0 + wc + n * 16 + lr;          // col=l&15
        if (OUT_BF16) ((unsigned short*)Cv)[row * N + col] = f2bf(acc[m][n][r]);
        else          ((float*)Cv)[row * N + col] = acc[m][n][r];
      }
}

// ---------------- RoPE Q (scale 1/8 folded) ----------------
__global__ void k_rope_q(const unsigned short* __restrict__ qkv,
                         const float* __restrict__ fc, const float* __restrict__ fs,
                         unsigned short* __restrict__ Qb)
{
  const int tid = blockIdx.x * 256 + threadIdx.x;    // NROWS*NH*32 total
  const int i = tid & 31;
  const int t2 = tid >> 5;
  const int h = t2 & 31;
  const int row = t2 >> 5;
  const int s = row & (SEQLEN - 1);
  const int b = row >> 11;
  const unsigned int u = *reinterpret_cast<const unsigned int*>(qkv + (size_t)row * NQKVC + h * HD + 2 * i);
  const float x0 = bf2f(u & 0xffffu), x1 = bf2f(u >> 16);
  const float c = fc[s * 32 + i], sn = fs[s * 32 + i];
  const float o0 = (x0 * c - x1 * sn) * 0.125f;
  const float o1 = (x0 * sn + x1 * c) * 0.125f;
  const unsigned int pk = (unsigned int)f2bf(o0) | ((unsigned int)f2bf(o1) << 16);
  *reinterpret_cast<unsigned int*>(Qb + ((size_t)((b * NH + h) * SEQLEN + s)) * HD + 2 * i) = pk;
}

// ---------------- RoPE K ----------------
__global__ void k_rope_k(const unsigned short* __restrict__ qkv,
                         const float* __restrict__ fc, const float* __restrict__ fs,
                         unsigned short* __restrict__ Kb)
{
  const int tid = blockIdx.x * 256 + threadIdx.x;    // NROWS*NKV*32 total
  const int i = tid & 31;
  const int t2 = tid >> 5;
  const int kv = t2 & 7;
  const int row = t2 >> 3;
  const int s = row & (SEQLEN - 1);
  const int b = row >> 11;
  const unsigned int u = *reinterpret_cast<const unsigned int*>(
      qkv + (size_t)row * NQKVC + DIMSZ + kv * HD + 2 * i);
  const float x0 = bf2f(u & 0xffffu), x1 = bf2f(u >> 16);
  const float c = fc[s * 32 + i], sn = fs[s * 32 + i];
  const float o0 = x0 * c - x1 * sn;
  const float o1 = x0 * sn + x1 * c;
  const unsigned int pk = (unsigned int)f2bf(o0) | ((unsigned int)f2bf(o1) << 16);
  *reinterpret_cast<unsigned int*>(Kb + ((size_t)((b * NKV + kv) * SEQLEN + s)) * HD + 2 * i) = pk;
}

// ---------------- V gather ----------------
__global__ void k_vcopy(const unsigned short* __restrict__ qkv, unsigned short* __restrict__ Vb) {
  const int tid = blockIdx.x * 256 + threadIdx.x;    // NROWS*NKV*8 chunks of 8
  const int c8 = tid & 7;
  const int t2 = tid >> 3;
  const int kv = t2 & 7;
  const int row = t2 >> 3;
  const int s = row & (SEQLEN - 1);
  const int b = row >> 11;
  const uint4 v = *reinterpret_cast<const uint4*>(
      qkv + (size_t)row * NQKVC + DIMSZ + NKV * HD + kv * HD + c8 * 8);
  *reinterpret_cast<uint4*>(Vb + ((size_t)((b * NKV + kv) * SEQLEN + s)) * HD + c8 * 8) = v;
}

// ---------------- flash attention ----------------
// block = (qtile of 128 rows, head, batch); 4 waves x 32 q rows.
__global__ __launch_bounds__(256, 2) void k_attn(
    const unsigned short* __restrict__ Qg,   // [B][NH][S][HD], pre-scaled 1/8
    const unsigned short* __restrict__ Kg,   // [B][NKV][S][HD]
    const unsigned short* __restrict__ Vg,   // [B][NKV][S][HD]
    unsigned short* __restrict__ Og)         // [B*S][NH*HD]
{
  constexpr int KVB = 64;
  __shared__ __attribute__((aligned(16))) unsigned short sK[KVB * HD];     // [kv][d] swizzled
  __shared__ __attribute__((aligned(16))) unsigned short sV[HD * KVB];     // [d][kv] swizzled
  __shared__ __attribute__((aligned(16))) unsigned short sP[4 * 32 * KVB]; // per-wave [32][kv]
  const int tid = threadIdx.x;
  const int lane = tid & 63, wid = tid >> 6;
  const int lr = lane & 15, lg = lane >> 4;
  const int qt = blockIdx.x, h = blockIdx.y, b = blockIdx.z;
  const int kvh = h >> 2;                    // rep = 4
  const int qbase = qt * 128;
  const int qrow0 = qbase + wid * 32;
  const unsigned short* Qp = Qg + ((size_t)(b * NH + h) * SEQLEN) * HD;
  const unsigned short* Kp = Kg + ((size_t)(b * NKV + kvh) * SEQLEN) * HD;
  const unsigned short* Vp = Vg + ((size_t)(b * NKV + kvh) * SEQLEN) * HD;
  unsigned short* Pw = sP + wid * (32 * KVB);

  // Q fragments, held in registers for the whole KV loop
  bf16x8 aq[2][2];
  #pragma unroll
  for (int m = 0; m < 2; m++)
    #pragma unroll
    for (int ks = 0; ks < 2; ks++)
      aq[m][ks] = *reinterpret_cast<const bf16x8*>(
          Qp + (size_t)(qrow0 + m * 16 + lr) * HD + ks * 32 + lg * 8);

  f32x4v accO[2][4];
  float mrun[2][4], lrun[2][4];
  #pragma unroll
  for (int m = 0; m < 2; m++)
    #pragma unroll
    for (int r = 0; r < 4; r++) {
      mrun[m][r] = -3.0e38f; lrun[m][r] = 0.f;
      if (r == 0) { accO[m][0] = f32x4v{0,0,0,0}; accO[m][1] = f32x4v{0,0,0,0};
                    accO[m][2] = f32x4v{0,0,0,0}; accO[m][3] = f32x4v{0,0,0,0}; }
    }

  const int nt = qt * 2 + 2;
  for (int t = 0; t < nt; t++) {
    const int kv0 = t * KVB;
    // cooperative staging of K tile and transposed V tile
    #pragma unroll
    for (int i = 0; i < 2; i++) {
      const int c = i * 256 + tid;
      const int row = c >> 3, kc = c & 7;
      uint4 kvec = *reinterpret_cast<const uint4*>(Kp + (size_t)(kv0 + row) * HD + kc * 8);
      *reinterpret_cast<uint4*>((char*)sK + swz128(row, kc * 16)) = kvec;
      uint4 vvec = *reinterpret_cast<const uint4*>(Vp + (size_t)(kv0 + row) * HD + kc * 8);
      const unsigned short* vs = reinterpret_cast<const unsigned short*>(&vvec);
      #pragma unroll
      for (int j = 0; j < 8; j++) {
        const int d = kc * 8 + j;
        *reinterpret_cast<unsigned short*>((char*)sV + swz128(d, row * 2)) = vs[j];
      }
    }
    __syncthreads();
    if (kv0 <= qrow0 + 31) {    // wave has at least one unmasked element
      f32x4v sfr[2][4];
      #pragma unroll
      for (int m = 0; m < 2; m++)
        #pragma unroll
        for (int c = 0; c < 4; c++)
          sfr[m][c] = f32x4v{0,0,0,0};
      // S = Q K^T
      #pragma unroll
      for (int ks = 0; ks < 2; ks++) {
        bf16x8 bk[4];
        #pragma unroll
        for (int c = 0; c < 4; c++)
          bk[c] = *reinterpret_cast<const bf16x8*>((char*)sK + swz128(c * 16 + lr, ks * 64 + lg * 16));
        #pragma unroll
        for (int m = 0; m < 2; m++)
          #pragma unroll
          for (int c = 0; c < 4; c++)
            sfr[m][c] = __builtin_amdgcn_mfma_f32_16x16x32_bf16(aq[m][ks], bk[c], sfr[m][c], 0, 0, 0);
      }
      // causal mask
      if (kv0 + KVB - 1 > qrow0) {
        #pragma unroll
        for (int m = 0; m < 2; m++)
          #pragma unroll
          for (int c = 0; c < 4; c++)
            #pragma unroll
            for (int r = 0; r < 4; r++) {
              const int q = qrow0 + m * 16 + lg * 4 + r;
              const int kv = kv0 + c * 16 + lr;
              if (kv > q) sfr[m][c][r] = -1.0e30f;
            }
      }
      // online softmax (rows live on 16-lane groups)
      #pragma unroll
      for (int m = 0; m < 2; m++) {
        #pragma unroll
        for (int r = 0; r < 4; r++) {
          float tm = fmaxf(fmaxf(sfr[m][0][r], sfr[m][1][r]), fmaxf(sfr[m][2][r], sfr[m][3][r]));
          tm = fmaxf(tm, __shfl_xor(tm, 1));
          tm = fmaxf(tm, __shfl_xor(tm, 2));
          tm = fmaxf(tm, __shfl_xor(tm, 4));
          tm = fmaxf(tm, __shfl_xor(tm, 8));
          const float mo = mrun[m][r];
          const float mn = fmaxf(mo, tm);
          const float sc = __expf(mo - mn);
          mrun[m][r] = mn;
          float rs = 0.f;
          #pragma unroll
          for (int c = 0; c < 4; c++) {
            const float p = __expf(sfr[m][c][r] - mn);
            sfr[m][c][r] = p;
            rs += p;
          }
          rs += __shfl_xor(rs, 1);
          rs += __shfl_xor(rs, 2);
          rs += __shfl_xor(rs, 4);
          rs += __shfl_xor(rs, 8);
          lrun[m][r] = lrun[m][r] * sc + rs;
          #pragma unroll
          for (int dc = 0; dc < 4; dc++) accO[m][dc][r] *= sc;
        }
      }
      // P -> LDS (C-layout scatter), re-read in A-layout
      #pragma unroll
      for (int m = 0; m < 2; m++)
        #pragma unroll
        for (int c = 0; c < 4; c++)
          #pragma unroll
          for (int r = 0; r < 4; r++)
            *reinterpret_cast<unsigned short*>(
                (char*)Pw + swz128(m * 16 + lg * 4 + r, (c * 16 + lr) * 2)) = f2bf(sfr[m][c][r]);
      // O += P V
      #pragma unroll
      for (int ks = 0; ks < 2; ks++) {
        bf16x8 ap[2], bv[4];
        #pragma unroll
        for (int m = 0; m < 2; m++)
          ap[m] = *reinterpret_cast<const bf16x8*>((char*)Pw + swz128(m * 16 + lr, ks * 64 + lg * 16));
        #pragma unroll
        for (int dc = 0; dc < 4; dc++)
          bv[dc] = *reinterpret_cast<const bf16x8*>((char*)sV + swz128(dc * 16 + lr, ks * 64 + lg * 16));
        #pragma unroll
        for (int m = 0; m < 2; m++)
          #pragma unroll
          for (int dc = 0; dc < 4; dc++)
            accO[m][dc] = __builtin_amdgcn_mfma_f32_16x16x32_bf16(ap[m], bv[dc], accO[m][dc], 0, 0, 0);
      }
    }
    __syncthreads();
  }
  // normalize + store
  #pragma unroll
  for (int m = 0; m < 2; m++)
    #pragma unroll
    for (int r = 0; r < 4; r++) {
      const float inv = 1.0f / lrun[m][r];
      const int q = qrow0 + m * 16 + lg * 4 + r;
      #pragma unroll
      for (int dc = 0; dc < 4; dc++) {
        const int d = dc * 16 + lr;
        Og[(size_t)(b * SEQLEN + q) * DIMSZ + h * HD + d] = f2bf(accO[m][dc][r] * inv);
      }
    }
}

extern "C" void kernel_launch(void* const* d_in, const int* in_sizes, int n_in,
                              void* d_out, int out_size, void* d_ws, size_t ws_size,
                              hipStream_t stream)
{
  const float* x  = (const float*)d_in[0];
  const float* fc = (const float*)d_in[1];
  const float* fs = (const float*)d_in[2];
  const float* wq = (const float*)d_in[3];
  const float* wk = (const float*)d_in[4];
  const float* wv = (const float*)d_in[5];
  const float* wo = (const float*)d_in[6];
  float* out = (float*)d_out;
  char* ws = (char*)d_ws;

  unsigned short* xb    = (unsigned short*)(ws + 0);          // 16.8 MB  [4096][2048]
  unsigned short* wqkvb = (unsigned short*)(ws + 16777216);   // 12.6 MB  [3072][2048]
  unsigned short* wob   = (unsigned short*)(ws + 29360128);   //  8.4 MB  [2048][2048]
  unsigned short* qkv   = (unsigned short*)(ws + 37748736);   // 25.2 MB  [4096][3072]
  unsigned short* Qb    = (unsigned short*)(ws + 62914560);   // 16.8 MB  [2][32][2048][64]
  unsigned short* Kb    = (unsigned short*)(ws + 79691776);   //  4.2 MB  [2][8][2048][64]
  unsigned short* Vb    = (unsigned short*)(ws + 83886080);   //  4.2 MB  [2][8][2048][64]
  unsigned short* attnb = (unsigned short*)(ws + 88080384);   // 16.8 MB  [4096][2048]

  k_cvt<<<8192, 256, 0, stream>>>(x,  xb, 2097152);
  k_cvt<<<4096, 256, 0, stream>>>(wq, wqkvb, 1048576);
  k_cvt<<<1024, 256, 0, stream>>>(wk, wqkvb + 2048 * 2048, 262144);
  k_cvt<<<1024, 256, 0, stream>>>(wv, wqkvb + 2560 * 2048, 262144);
  k_cvt<<<4096, 256, 0, stream>>>(wo, wob, 1048576);

  dim3 g1(24, 32);   // N=3072/128, M=4096/128
  k_gemm_bt<1><<<g1, 256, 0, stream>>>(xb, wqkvb, qkv, NROWS, NQKVC, DIMSZ);

  k_rope_q<<<16384, 256, 0, stream>>>(qkv, fc, fs, Qb);
  k_rope_k<<<4096, 256, 0, stream>>>(qkv, fc, fs, Kb);
  k_vcopy<<<1024, 256, 0, stream>>>(qkv, Vb);

  dim3 ga(16, 32, 2);  // qtiles, heads, batch
  k_attn<<<ga, 256, 0, stream>>>(Qb, Kb, Vb, attnb);

  dim3 g2(16, 32);     // N=2048/128, M=4096/128
  k_gemm_bt<0><<<g2, 256, 0, stream>>>(attnb, wob, out, NROWS, DIMSZ, DIMSZ);
}

// Round 3
// 231.858 us; speedup vs baseline: 2.8598x; 2.8598x over previous
//
#include <hip/hip_runtime.h>

#define DIMSZ 2048
#define NH 32
#define NKV 8
#define HD 64
#define SEQLEN 2048
#define BATCH 2
#define NROWS (BATCH*SEQLEN)   // 4096
#define NQKVC 3072             // 2048 q + 512 k + 512 v

typedef __bf16 bf16x8 __attribute__((ext_vector_type(8)));
typedef float f32x4v __attribute__((ext_vector_type(4)));

__device__ __forceinline__ unsigned short f2bf(float f) {
  union { float f; unsigned int u; } v; v.f = f;
  return (unsigned short)((v.u + 0x7FFFu + ((v.u >> 16) & 1u)) >> 16);
}
__device__ __forceinline__ float bf2f(unsigned int bits16) {
  union { unsigned int u; float f; } v; v.u = bits16 << 16; return v.f;
}
// XOR swizzle for LDS tiles with 128-byte rows.
__device__ __forceinline__ int swz128(int row, int colBytes) {
  return row * 128 + (colBytes ^ ((row & 7) << 4));
}

// async global->LDS, 16B per lane. LDS dest is the wave-uniform chunk base
// (HW adds lane*16); global source is per-lane inverse-swizzled (rule #21).
#define GLOAD16(g, l) __builtin_amdgcn_global_load_lds( \
    (const __attribute__((address_space(1))) unsigned int*)(g), \
    (__attribute__((address_space(3))) unsigned int*)(l), 16, 0, 0)

// ---------------- fp32 -> bf16 convert (vectorized x4) ----------------
__global__ void k_cvt(const float* __restrict__ s, unsigned short* __restrict__ d, int n4) {
  int i = blockIdx.x * 256 + threadIdx.x;
  if (i >= n4) return;
  float4 v = reinterpret_cast<const float4*>(s)[i];
  unsigned long long pk =
      (unsigned long long)f2bf(v.x) |
      ((unsigned long long)f2bf(v.y) << 16) |
      ((unsigned long long)f2bf(v.z) << 32) |
      ((unsigned long long)f2bf(v.w) << 48);
  reinterpret_cast<unsigned long long*>(d)[i] = pk;
}

// ---------------- GEMM: C[M][N] = A[M][K] * B[N][K]^T ----------------
// 128x128 tile, BK=64, global_load_lds staging (m97 2-barrier structure).
template<int OUT_BF16>
__global__ __launch_bounds__(256, 2) void k_gemm_bt(
    const unsigned short* __restrict__ A,
    const unsigned short* __restrict__ B,
    void* __restrict__ Cv, int M, int N, int K)
{
  constexpr int BK = 64;
  __shared__ __attribute__((aligned(16))) unsigned short smA[128 * BK];
  __shared__ __attribute__((aligned(16))) unsigned short smB[128 * BK];
  const int tid = threadIdx.x;
  const int lane = tid & 63;
  const int wid = tid >> 6;
  const int lr = lane & 15, lg = lane >> 4;
  const int m0 = blockIdx.y * 128, n0 = blockIdx.x * 128;
  const int wr = (wid >> 1) * 64, wc = (wid & 1) * 64;

  f32x4v acc[4][4];
  #pragma unroll
  for (int i = 0; i < 4; i++)
    #pragma unroll
    for (int j = 0; j < 4; j++)
      acc[i][j] = f32x4v{0.f, 0.f, 0.f, 0.f};

  for (int k0 = 0; k0 < K; k0 += BK) {
    // stage A and B tiles: 16 chunks of 1KB each, wave wid owns chunks wid*4..wid*4+3
    #pragma unroll
    for (int c = 0; c < 4; c++) {
      const int chunk = wid * 4 + c;
      const int idx = chunk * 64 + lane;
      const int row = idx >> 3, s = idx & 7;
      const int ks = (s ^ (row & 7)) * 8;
      GLOAD16(A + (size_t)(m0 + row) * K + k0 + ks, &smA[chunk * 512]);
      GLOAD16(B + (size_t)(n0 + row) * K + k0 + ks, &smB[chunk * 512]);
    }
    __syncthreads();   // vmcnt(0) drained by compiler before barrier
    #pragma unroll
    for (int ks = 0; ks < 2; ks++) {
      bf16x8 af[4], bfv[4];
      #pragma unroll
      for (int m = 0; m < 4; m++)
        af[m] = *reinterpret_cast<const bf16x8*>((char*)smA + swz128(wr + m * 16 + lr, ks * 64 + lg * 16));
      #pragma unroll
      for (int n = 0; n < 4; n++)
        bfv[n] = *reinterpret_cast<const bf16x8*>((char*)smB + swz128(wc + n * 16 + lr, ks * 64 + lg * 16));
      #pragma unroll
      for (int m = 0; m < 4; m++)
        #pragma unroll
        for (int n = 0; n < 4; n++)
          acc[m][n] = __builtin_amdgcn_mfma_f32_16x16x32_bf16(af[m], bfv[n], acc[m][n], 0, 0, 0);
    }
    __syncthreads();   // protect LDS before next tile's async writes
  }
  #pragma unroll
  for (int m = 0; m < 4; m++)
    #pragma unroll
    for (int n = 0; n < 4; n++)
      #pragma unroll
      for (int r = 0; r < 4; r++) {
        const size_t row = m0 + wr + m * 16 + lg * 4 + r;  // C/D: row=(l>>4)*4+r
        const size_t col = n0 + wc + n * 16 + lr;          // col=l&15
        if (OUT_BF16) ((unsigned short*)Cv)[row * N + col] = f2bf(acc[m][n][r]);
        else          ((float*)Cv)[row * N + col] = acc[m][n][r];
      }
}

// ---------------- RoPE Q (scale 1/8 folded) ----------------
__global__ void k_rope_q(const unsigned short* __restrict__ qkv,
                         const float* __restrict__ fc, const float* __restrict__ fs,
                         unsigned short* __restrict__ Qb)
{
  const int tid = blockIdx.x * 256 + threadIdx.x;
  const int i = tid & 31;
  const int t2 = tid >> 5;
  const int h = t2 & 31;
  const int row = t2 >> 5;
  const int s = row & (SEQLEN - 1);
  const int b = row >> 11;
  const unsigned int u = *reinterpret_cast<const unsigned int*>(qkv + (size_t)row * NQKVC + h * HD + 2 * i);
  const float x0 = bf2f(u & 0xffffu), x1 = bf2f(u >> 16);
  const float c = fc[s * 32 + i], sn = fs[s * 32 + i];
  const float o0 = (x0 * c - x1 * sn) * 0.125f;
  const float o1 = (x0 * sn + x1 * c) * 0.125f;
  const unsigned int pk = (unsigned int)f2bf(o0) | ((unsigned int)f2bf(o1) << 16);
  *reinterpret_cast<unsigned int*>(Qb + ((size_t)((b * NH + h) * SEQLEN + s)) * HD + 2 * i) = pk;
}

// ---------------- RoPE K ----------------
__global__ void k_rope_k(const unsigned short* __restrict__ qkv,
                         const float* __restrict__ fc, const float* __restrict__ fs,
                         unsigned short* __restrict__ Kb)
{
  const int tid = blockIdx.x * 256 + threadIdx.x;
  const int i = tid & 31;
  const int t2 = tid >> 5;
  const int kv = t2 & 7;
  const int row = t2 >> 3;
  const int s = row & (SEQLEN - 1);
  const int b = row >> 11;
  const unsigned int u = *reinterpret_cast<const unsigned int*>(
      qkv + (size_t)row * NQKVC + DIMSZ + kv * HD + 2 * i);
  const float x0 = bf2f(u & 0xffffu), x1 = bf2f(u >> 16);
  const float c = fc[s * 32 + i], sn = fs[s * 32 + i];
  const float o0 = x0 * c - x1 * sn;
  const float o1 = x0 * sn + x1 * c;
  const unsigned int pk = (unsigned int)f2bf(o0) | ((unsigned int)f2bf(o1) << 16);
  *reinterpret_cast<unsigned int*>(Kb + ((size_t)((b * NKV + kv) * SEQLEN + s)) * HD + 2 * i) = pk;
}

// ---------------- V transpose: qkv -> Vt[b][kv][d][s] ----------------
// FIX (round 2 bug): load phase must cover all 64 tile rows — each thread
// now loads 2 rows. Previously rows 32..63 held the 0xAA poison.
__global__ void k_vt(const unsigned short* __restrict__ qkv, unsigned short* __restrict__ Vt) {
  __shared__ unsigned short tile[64][72];
  const int st = blockIdx.x, kv = blockIdx.y, b = blockIdx.z;
  const int tid = threadIdx.x;
  #pragma unroll
  for (int j2 = 0; j2 < 2; j2++) {
    const int s = (tid >> 3) + j2 * 32, dc = (tid & 7) * 8;
    const int row = b * SEQLEN + st * 64 + s;
    uint4 v = *reinterpret_cast<const uint4*>(
        qkv + (size_t)row * NQKVC + DIMSZ + NKV * HD + kv * HD + dc);
    const unsigned short* vs = reinterpret_cast<const unsigned short*>(&v);
    #pragma unroll
    for (int j = 0; j < 8; j++) tile[s][dc + j] = vs[j];
  }
  __syncthreads();
  {
    const int d = tid >> 2, sc = (tid & 3) * 16;
    unsigned short tmp[16];
    #pragma unroll
    for (int j = 0; j < 16; j++) tmp[j] = tile[sc + j][d];
    unsigned short* outp = Vt + ((size_t)((b * NKV + kv) * HD) + d) * SEQLEN + st * 64 + sc;
    *reinterpret_cast<uint4*>(outp)     = *reinterpret_cast<uint4*>(tmp);
    *reinterpret_cast<uint4*>(outp + 8) = *reinterpret_cast<uint4*>(tmp + 8);
  }
}

// ---------------- flash attention ----------------
// 512 threads = 8 waves x 16 q-rows = 128-row q-tile; block handles the
// q-tile PAIR (qp, 15-qp) for uniform causal work (34 KV tiles/block).
__global__ __launch_bounds__(512, 2) void k_attn(
    const unsigned short* __restrict__ Qg,   // [B][NH][S][HD], pre-scaled 1/8
    const unsigned short* __restrict__ Kg,   // [B][NKV][S][HD]
    const unsigned short* __restrict__ Vt,   // [B][NKV][HD][S]
    unsigned short* __restrict__ Og)         // [B*S][NH*HD]
{
  constexpr int KVB = 64;
  __shared__ __attribute__((aligned(16))) unsigned short sK[KVB * HD];      // [kv][d] swz
  __shared__ __attribute__((aligned(16))) unsigned short sV[HD * KVB];      // [d][kv] swz
  __shared__ __attribute__((aligned(16))) unsigned short sP[8 * 16 * KVB];  // per-wave [16][kv]
  const int tid = threadIdx.x;
  const int lane = tid & 63, wid = tid >> 6;
  const int lr = lane & 15, lg = lane >> 4;
  const int qp = blockIdx.x, h = blockIdx.y, b = blockIdx.z;
  const int kvh = h >> 2;
  const unsigned short* Qp = Qg + ((size_t)(b * NH + h) * SEQLEN) * HD;
  const unsigned short* Kp = Kg + ((size_t)(b * NKV + kvh) * SEQLEN) * HD;
  const unsigned short* Vp = Vt + ((size_t)(b * NKV + kvh) * HD) * SEQLEN;
  unsigned short* Pw = sP + wid * (16 * KVB);

  // staging geometry (same for K and V tiles): wave wid owns 1KB chunk wid
  const int sidx = wid * 64 + lane;
  const int srow = sidx >> 3;                 // kv row (K) / d row (V)
  const int scol = ((sidx & 7) ^ (srow & 7)) * 8;

  for (int phase = 0; phase < 2; phase++) {
    const int qt = phase ? (15 - qp) : qp;
    const int qrow0 = qt * 128 + wid * 16;
    bf16x8 aq[2];
    #pragma unroll
    for (int ks = 0; ks < 2; ks++)
      aq[ks] = *reinterpret_cast<const bf16x8*>(Qp + (size_t)(qrow0 + lr) * HD + ks * 32 + lg * 8);

    f32x4v accO[4];
    float mrun[4], lrun[4];
    #pragma unroll
    for (int r = 0; r < 4; r++) {
      accO[r] = f32x4v{0.f, 0.f, 0.f, 0.f};
      mrun[r] = -3.0e38f; lrun[r] = 0.f;
    }

    const int nt = qt * 2 + 2;
    for (int t = 0; t < nt; t++) {
      const int kv0 = t * KVB;
      GLOAD16(Kp + (size_t)(kv0 + srow) * HD + scol, &sK[wid * 512]);
      GLOAD16(Vp + (size_t)srow * SEQLEN + kv0 + scol, &sV[wid * 512]);
      __syncthreads();
      if (kv0 <= qrow0 + 15) {
        f32x4v sfr[4];
        #pragma unroll
        for (int c = 0; c < 4; c++) sfr[c] = f32x4v{0.f, 0.f, 0.f, 0.f};
        __builtin_amdgcn_s_setprio(1);
        #pragma unroll
        for (int ks = 0; ks < 2; ks++) {
          bf16x8 bk[4];
          #pragma unroll
          for (int c = 0; c < 4; c++)
            bk[c] = *reinterpret_cast<const bf16x8*>((char*)sK + swz128(c * 16 + lr, ks * 64 + lg * 16));
          #pragma unroll
          for (int c = 0; c < 4; c++)
            sfr[c] = __builtin_amdgcn_mfma_f32_16x16x32_bf16(aq[ks], bk[c], sfr[c], 0, 0, 0);
        }
        __builtin_amdgcn_s_setprio(0);
        if (kv0 + KVB - 1 > qrow0) {
          #pragma unroll
          for (int c = 0; c < 4; c++)
            #pragma unroll
            for (int r = 0; r < 4; r++) {
              const int q = qrow0 + lg * 4 + r;
              const int kv = kv0 + c * 16 + lr;
              if (kv > q) sfr[c][r] = -1.0e30f;
            }
        }
        #pragma unroll
        for (int r = 0; r < 4; r++) {
          float tm = fmaxf(fmaxf(sfr[0][r], sfr[1][r]), fmaxf(sfr[2][r], sfr[3][r]));
          tm = fmaxf(tm, __shfl_xor(tm, 1));
          tm = fmaxf(tm, __shfl_xor(tm, 2));
          tm = fmaxf(tm, __shfl_xor(tm, 4));
          tm = fmaxf(tm, __shfl_xor(tm, 8));
          const float mo = mrun[r];
          const float mn = fmaxf(mo, tm);
          const float sc = __expf(mo - mn);
          mrun[r] = mn;
          float rs = 0.f;
          #pragma unroll
          for (int c = 0; c < 4; c++) {
            const float p = __expf(sfr[c][r] - mn);
            sfr[c][r] = p;
            rs += p;
          }
          rs += __shfl_xor(rs, 1);
          rs += __shfl_xor(rs, 2);
          rs += __shfl_xor(rs, 4);
          rs += __shfl_xor(rs, 8);
          lrun[r] = lrun[r] * sc + rs;
          #pragma unroll
          for (int dc = 0; dc < 4; dc++) accO[dc][r] *= sc;
        }
        // P -> per-wave LDS (C-layout scatter), re-read in A-layout
        #pragma unroll
        for (int c = 0; c < 4; c++)
          #pragma unroll
          for (int r = 0; r < 4; r++)
            *reinterpret_cast<unsigned short*>(
                (char*)Pw + swz128(lg * 4 + r, (c * 16 + lr) * 2)) = f2bf(sfr[c][r]);
        __builtin_amdgcn_s_setprio(1);
        #pragma unroll
        for (int ks = 0; ks < 2; ks++) {
          bf16x8 ap = *reinterpret_cast<const bf16x8*>((char*)Pw + swz128(lr, ks * 64 + lg * 16));
          bf16x8 bv[4];
          #pragma unroll
          for (int dc = 0; dc < 4; dc++)
            bv[dc] = *reinterpret_cast<const bf16x8*>((char*)sV + swz128(dc * 16 + lr, ks * 64 + lg * 16));
          #pragma unroll
          for (int dc = 0; dc < 4; dc++)
            accO[dc] = __builtin_amdgcn_mfma_f32_16x16x32_bf16(ap, bv[dc], accO[dc], 0, 0, 0);
        }
        __builtin_amdgcn_s_setprio(0);
      }
      __syncthreads();
    }
    // normalize + store
    #pragma unroll
    for (int r = 0; r < 4; r++) {
      const float inv = 1.0f / lrun[r];
      const int q = qrow0 + lg * 4 + r;
      #pragma unroll
      for (int dc = 0; dc < 4; dc++) {
        const int d = dc * 16 + lr;
        Og[(size_t)(b * SEQLEN + q) * DIMSZ + h * HD + d] = f2bf(accO[dc][r] * inv);
      }
    }
  }
}

extern "C" void kernel_launch(void* const* d_in, const int* in_sizes, int n_in,
                              void* d_out, int out_size, void* d_ws, size_t ws_size,
                              hipStream_t stream)
{
  const float* x  = (const float*)d_in[0];
  const float* fc = (const float*)d_in[1];
  const float* fs = (const float*)d_in[2];
  const float* wq = (const float*)d_in[3];
  const float* wk = (const float*)d_in[4];
  const float* wv = (const float*)d_in[5];
  const float* wo = (const float*)d_in[6];
  float* out = (float*)d_out;
  char* ws = (char*)d_ws;

  unsigned short* xb    = (unsigned short*)(ws + 0);          // [4096][2048]
  unsigned short* wqkvb = (unsigned short*)(ws + 16777216);   // [3072][2048]
  unsigned short* wob   = (unsigned short*)(ws + 29360128);   // [2048][2048]
  unsigned short* qkv   = (unsigned short*)(ws + 37748736);   // [4096][3072]
  unsigned short* Qb    = (unsigned short*)(ws + 62914560);   // [2][32][2048][64]
  unsigned short* Kb    = (unsigned short*)(ws + 79691776);   // [2][8][2048][64]
  unsigned short* Vtb   = (unsigned short*)(ws + 83886080);   // [2][8][64][2048]
  unsigned short* attnb = (unsigned short*)(ws + 88080384);   // [4096][2048]

  k_cvt<<<8192, 256, 0, stream>>>(x,  xb, 2097152);
  k_cvt<<<4096, 256, 0, stream>>>(wq, wqkvb, 1048576);
  k_cvt<<<1024, 256, 0, stream>>>(wk, wqkvb + 2048 * 2048, 262144);
  k_cvt<<<1024, 256, 0, stream>>>(wv, wqkvb + 2560 * 2048, 262144);
  k_cvt<<<4096, 256, 0, stream>>>(wo, wob, 1048576);

  dim3 g1(24, 32);   // N=3072/128, M=4096/128
  k_gemm_bt<1><<<g1, 256, 0, stream>>>(xb, wqkvb, qkv, NROWS, NQKVC, DIMSZ);

  k_rope_q<<<16384, 256, 0, stream>>>(qkv, fc, fs, Qb);
  k_rope_k<<<4096, 256, 0, stream>>>(qkv, fc, fs, Kb);
  dim3 gv(32, 8, 2);
  k_vt<<<gv, 256, 0, stream>>>(qkv, Vtb);

  dim3 ga(8, 32, 2);   // q-tile pairs, heads, batch
  k_attn<<<ga, 512, 0, stream>>>(Qb, Kb, Vtb, attnb);

  dim3 g2(16, 32);     // N=2048/128, M=4096/128
  k_gemm_bt<0><<<g2, 256, 0, stream>>>(attnb, wob, out, NROWS, DIMSZ, DIMSZ);
}